// Round 1
// baseline (1093.707 us; speedup 1.0000x reference)
//
#include <hip/hip_runtime.h>
#include <cstdint>
#include <cstddef>

typedef __bf16 bf16_t;
typedef __bf16 bf16x8 __attribute__((ext_vector_type(8)));
typedef float floatx4 __attribute__((ext_vector_type(4)));

#define B_ 4
#define S_ 2048
#define E_ 1024
#define SV_ 50
#define SVP_ 64

// ---------------- elementwise tanh + cast ----------------
__global__ __launch_bounds__(256) void tanh_cast_k(const float* __restrict__ in,
                                                   bf16_t* __restrict__ out, long n) {
  long i = (long)blockIdx.x * 256 + threadIdx.x;
  if (i < n) out[i] = (bf16_t)tanhf(in[i]);
}

// V [B,50,1024] -> tanh, padded to [B,64,1024] with zero rows
__global__ __launch_bounds__(256) void tanh_vpad_k(const float* __restrict__ V,
                                                   bf16_t* __restrict__ out) {
  int i = blockIdx.x * 256 + threadIdx.x;  // covers B*64*1024
  int e = i & 1023, r = (i >> 10) & 63, b = i >> 16;
  float v = 0.f;
  if (r < SV_) v = tanhf(V[((long)(b * SV_ + r) << 10) + e]);
  out[i] = (bf16_t)v;
}

// ---------------- W [K,N] fp32 -> Wt [N,Kp] bf16 (zero-pad k>=K) ----------------
__global__ __launch_bounds__(256) void transp_cast_k(const float* __restrict__ W,
                                                     bf16_t* __restrict__ out,
                                                     int K, int N, int Kp) {
  __shared__ float tile[32][33];
  int k0 = blockIdx.y * 32, n0 = blockIdx.x * 32;
  int tx = threadIdx.x, ty = threadIdx.y;  // block (32,8)
#pragma unroll
  for (int s2 = 0; s2 < 4; ++s2) {
    int kk = ty + s2 * 8;
    float v = 0.f;
    if (k0 + kk < K && n0 + tx < N) v = W[(long)(k0 + kk) * N + n0 + tx];
    tile[kk][tx] = v;
  }
  __syncthreads();
#pragma unroll
  for (int s2 = 0; s2 < 4; ++s2) {
    int nn = ty + s2 * 8;
    if (n0 + nn < N && k0 + tx < Kp)
      out[(long)(n0 + nn) * Kp + k0 + tx] = (bf16_t)tile[tx][nn];
  }
}

// ---------------- per-batch bf16 transpose [R,C] -> [C,R] ----------------
__global__ __launch_bounds__(256) void transp_bf16_k(const bf16_t* __restrict__ in,
                                                     bf16_t* __restrict__ out,
                                                     int R, int C) {
  __shared__ bf16_t tile[32][33];
  long boff = (long)blockIdx.z * R * C;
  int r0 = blockIdx.y * 32, c0 = blockIdx.x * 32;
  int tx = threadIdx.x, ty = threadIdx.y;  // block (32,8)
#pragma unroll
  for (int s2 = 0; s2 < 4; ++s2)
    tile[ty + s2 * 8][tx] = in[boff + (long)(r0 + ty + s2 * 8) * C + c0 + tx];
  __syncthreads();
#pragma unroll
  for (int s2 = 0; s2 < 4; ++s2)
    out[boff + (long)(c0 + ty + s2 * 8) * R + r0 + tx] = tile[tx][ty + s2 * 8];
}

// ---------------- column-sum over t of bf16 [B,S,E] -> fp32 [B,E] ----------------
__global__ __launch_bounds__(256) void colsum_part_k(const bf16_t* __restrict__ X,
                                                     float* __restrict__ part) {
  // grid (E/256, 8, B); part [B][8][E]
  int e = blockIdx.x * 256 + threadIdx.x;
  int chunk = blockIdx.y, b = blockIdx.z;
  const bf16_t* p = X + ((long)b * S_ + (long)chunk * 256) * E_ + e;
  float s = 0.f;
#pragma unroll 8
  for (int t = 0; t < 256; ++t) s += (float)p[(long)t * E_];
  part[((long)b * 8 + chunk) * E_ + e] = s;
}

__global__ __launch_bounds__(256) void colsum_fin_k(const float* __restrict__ part,
                                                    float* __restrict__ out) {
  // grid (E/256, B)
  int e = blockIdx.x * 256 + threadIdx.x;
  int b = blockIdx.y;
  float s = 0.f;
#pragma unroll
  for (int c = 0; c < 8; ++c) s += part[((long)b * 8 + c) * E_ + e];
  out[(long)b * E_ + e] = s;
}

// ---------------- row softmax (in-place on fp32 logits) + bf16 copy ----------------
__global__ __launch_bounds__(256) void softmax_row_k(float* __restrict__ logits,
                                                     bf16_t* __restrict__ fb) {
  long off = ((long)blockIdx.y * S_ + blockIdx.x) * S_;
  float* p = logits + off;
  bf16_t* pb = fb + off;
  int t = threadIdx.x;
  float x[8];
  float mx = -3.4e38f;
#pragma unroll
  for (int i = 0; i < 8; ++i) {
    x[i] = p[t + 256 * i];
    mx = fmaxf(mx, x[i]);
  }
  __shared__ float red[256];
  red[t] = mx;
  __syncthreads();
#pragma unroll
  for (int s = 128; s >= 1; s >>= 1) {
    if (t < s) red[t] = fmaxf(red[t], red[t + s]);
    __syncthreads();
  }
  mx = red[0];
  __syncthreads();
  float sum = 0.f;
#pragma unroll
  for (int i = 0; i < 8; ++i) {
    x[i] = __expf(x[i] - mx);
    sum += x[i];
  }
  red[t] = sum;
  __syncthreads();
#pragma unroll
  for (int s = 128; s >= 1; s >>= 1) {
    if (t < s) red[t] += red[t + s];
    __syncthreads();
  }
  float inv = 1.0f / red[0];
#pragma unroll
  for (int i = 0; i < 8; ++i) {
    float v = x[i] * inv;
    p[t + 256 * i] = v;
    pb[t + 256 * i] = (bf16_t)v;
  }
}

// ---------------- NT GEMM: C[m,n] = alpha*(+/-)sum_k A[m,k]B[n,k] (+Cadd)(+colVec) ----
// A: [M,K] row-major (row stride K); B: [N,K] row-major; out ld = N.
// All of M, N multiples of 64; K multiple of 64. 256 threads, 64x64 tile, BK=64.
__global__ __launch_bounds__(256) void gemm_nt_k(
    const bf16_t* __restrict__ A, const bf16_t* __restrict__ B,
    int N, int K, long sA, long sB, long sO, long sC, long sV,
    float alpha, int negAcc,
    const bf16_t* __restrict__ Cadd, const float* __restrict__ colVec,
    float* __restrict__ outF, bf16_t* __restrict__ outB) {
  __shared__ __align__(16) bf16_t As[64 * 64];
  __shared__ __align__(16) bf16_t Bs[64 * 64];
  const int t = threadIdx.x;
  const int lane = t & 63;
  const int wave = t >> 6;
  const int wm = (wave & 1) * 32;
  const int wn = (wave >> 1) * 32;
  const long b = blockIdx.z;
  const bf16_t* Ab = A + b * sA;
  const bf16_t* Bb = B + b * sB;
  const long rowBase = (long)blockIdx.y * 64;
  const long colBase = (long)blockIdx.x * 64;

  floatx4 acc[2][2];
#pragma unroll
  for (int i = 0; i < 2; ++i)
#pragma unroll
    for (int j = 0; j < 2; ++j) acc[i][j] = {0.f, 0.f, 0.f, 0.f};

  const int sr = t >> 3;       // staging row 0..31
  const int sc = (t & 7) * 8;  // staging col element 0..56 (16B chunks)
  for (int k0 = 0; k0 < K; k0 += 64) {
#pragma unroll
    for (int p = 0; p < 2; ++p) {
      int r = p * 32 + sr;
      *(uint4*)&As[r * 64 + sc] = *(const uint4*)&Ab[(rowBase + r) * K + k0 + sc];
      *(uint4*)&Bs[r * 64 + sc] = *(const uint4*)&Bb[(colBase + r) * K + k0 + sc];
    }
    __syncthreads();
#pragma unroll
    for (int ks = 0; ks < 64; ks += 32) {
      const int fr = lane & 15;
      const int fk = ks + ((lane >> 4) << 3);
      bf16x8 a0 = *(const bf16x8*)&As[(wm + fr) * 64 + fk];
      bf16x8 a1 = *(const bf16x8*)&As[(wm + 16 + fr) * 64 + fk];
      bf16x8 b0 = *(const bf16x8*)&Bs[(wn + fr) * 64 + fk];
      bf16x8 b1 = *(const bf16x8*)&Bs[(wn + 16 + fr) * 64 + fk];
      acc[0][0] = __builtin_amdgcn_mfma_f32_16x16x32_bf16(a0, b0, acc[0][0], 0, 0, 0);
      acc[0][1] = __builtin_amdgcn_mfma_f32_16x16x32_bf16(a0, b1, acc[0][1], 0, 0, 0);
      acc[1][0] = __builtin_amdgcn_mfma_f32_16x16x32_bf16(a1, b0, acc[1][0], 0, 0, 0);
      acc[1][1] = __builtin_amdgcn_mfma_f32_16x16x32_bf16(a1, b1, acc[1][1], 0, 0, 0);
    }
    __syncthreads();
  }

  const int cr = lane & 15;
  const int rq = (lane >> 4) * 4;
#pragma unroll
  for (int i = 0; i < 2; ++i)
#pragma unroll
    for (int j = 0; j < 2; ++j)
#pragma unroll
      for (int r = 0; r < 4; ++r) {
        long row = rowBase + wm + i * 16 + rq + r;
        long col = colBase + wn + j * 16 + cr;
        float v = alpha * acc[i][j][r];
        if (negAcc) v = -v;
        if (Cadd) v += (float)Cadd[b * sC + row * N + col];
        if (colVec) v += colVec[b * sV + col];
        long o = b * sO + row * N + col;
        if (outF) outF[o] = v;
        if (outB) outB[o] = (bf16_t)v;
      }
}

extern "C" void kernel_launch(void* const* d_in, const int* in_sizes, int n_in,
                              void* d_out, int out_size, void* d_ws, size_t ws_size,
                              hipStream_t stream) {
  const float* Q = (const float*)d_in[0];
  const float* Kin = (const float*)d_in[1];
  const float* V = (const float*)d_in[2];
  const float* W_Q = (const float*)d_in[3];
  const float* W_K = (const float*)d_in[4];
  const float* W_v = (const float*)d_in[5];
  const float* W_vq = (const float*)d_in[6];
  const float* W_vk = (const float*)d_in[7];

  float* Qout = (float*)d_out;                  // [4,2048,1024]
  float* Kout = Qout + (long)B_ * S_ * E_;      // [4,2048,1024]
  float* Fout = Kout + (long)B_ * S_ * E_;      // [4,2048,2048] (also logits scratch)

  char* w = (char*)d_ws;
  auto alloc = [&](size_t bytes) {
    char* p = w;
    w += (bytes + 255) & ~(size_t)255;
    return p;
  };
  bf16_t* WQt = (bf16_t*)alloc((size_t)2 * E_ * E_);
  bf16_t* WKt = (bf16_t*)alloc((size_t)2 * E_ * E_);
  bf16_t* WVt = (bf16_t*)alloc((size_t)2 * E_ * E_);
  bf16_t* WvqT = (bf16_t*)alloc((size_t)2 * E_ * SVP_);
  bf16_t* WvkT = (bf16_t*)alloc((size_t)2 * E_ * SVP_);
  bf16_t* Qt = (bf16_t*)alloc((size_t)2 * B_ * S_ * E_);  // later reused as q2
  bf16_t* Kt = (bf16_t*)alloc((size_t)2 * B_ * S_ * E_);  // later reused as k2
  bf16_t* Vt = (bf16_t*)alloc((size_t)2 * B_ * SVP_ * E_);
  bf16_t* qb = (bf16_t*)alloc((size_t)2 * B_ * S_ * E_);  // later reused as q2T
  bf16_t* kb = (bf16_t*)alloc((size_t)2 * B_ * S_ * E_);  // later reused as k2T
  bf16_t* vb = (bf16_t*)alloc((size_t)2 * B_ * SVP_ * E_);
  bf16_t* qT = (bf16_t*)alloc((size_t)2 * B_ * S_ * E_);
  bf16_t* kT = (bf16_t*)alloc((size_t)2 * B_ * S_ * E_);
  bf16_t* fb = (bf16_t*)alloc((size_t)2 * B_ * S_ * S_);
  bf16_t* vqf = (bf16_t*)alloc((size_t)2 * B_ * S_ * SVP_);
  bf16_t* vkf = (bf16_t*)alloc((size_t)2 * B_ * S_ * SVP_);
  bf16_t* Tmp = (bf16_t*)alloc((size_t)2 * B_ * S_ * E_);
  float* part = (float*)alloc((size_t)4 * B_ * 8 * E_);
  float* ck = (float*)alloc((size_t)4 * B_ * E_);
  float* ck2 = (float*)alloc((size_t)4 * B_ * E_);
  bf16_t* q2 = Qt;
  bf16_t* k2 = Kt;
  bf16_t* q2T = qb;
  bf16_t* k2T = kb;

  dim3 blk256(256);
  dim3 blk32x8(32, 8);

  auto gemm = [&](const bf16_t* A, const bf16_t* Bp, int M, int N, int K,
                  long sA, long sB, long sO, int nb, float alpha, int negAcc,
                  const bf16_t* Cadd, long sC, const float* colVec, long sV,
                  float* outF, bf16_t* outB) {
    gemm_nt_k<<<dim3(N / 64, M / 64, nb), dim3(256), 0, stream>>>(
        A, Bp, N, K, sA, sB, sO, sC, sV, alpha, negAcc, Cadd, colVec, outF, outB);
  };

  // ---- weight prep: W[K,N] fp32 -> [N,Kp] bf16 ----
  transp_cast_k<<<dim3(32, 32), blk32x8, 0, stream>>>(W_Q, WQt, E_, E_, E_);
  transp_cast_k<<<dim3(32, 32), blk32x8, 0, stream>>>(W_K, WKt, E_, E_, E_);
  transp_cast_k<<<dim3(32, 32), blk32x8, 0, stream>>>(W_v, WVt, E_, E_, E_);
  transp_cast_k<<<dim3(32, 2), blk32x8, 0, stream>>>(W_vq, WvqT, SV_, E_, SVP_);
  transp_cast_k<<<dim3(32, 2), blk32x8, 0, stream>>>(W_vk, WvkT, SV_, E_, SVP_);

  // ---- tanh + cast inputs ----
  long nQ = (long)B_ * S_ * E_;
  tanh_cast_k<<<dim3((unsigned)(nQ / 256)), blk256, 0, stream>>>(Q, Qt, nQ);
  tanh_cast_k<<<dim3((unsigned)(nQ / 256)), blk256, 0, stream>>>(Kin, Kt, nQ);
  tanh_vpad_k<<<dim3(B_ * SVP_ * E_ / 256), blk256, 0, stream>>>(V, Vt);

  // ---- projections (flat over B*S) ----
  gemm(Qt, WQt, B_ * S_, E_, E_, 0, 0, 0, 1, 1.f, 0, nullptr, 0, nullptr, 0, nullptr, qb);
  gemm(Kt, WKt, B_ * S_, E_, E_, 0, 0, 0, 1, 1.f, 0, nullptr, 0, nullptr, 0, nullptr, kb);
  gemm(Vt, WVt, B_ * SVP_, E_, E_, 0, 0, 0, 1, 1.f, 0, nullptr, 0, nullptr, 0, nullptr, vb);

  // ---- transposes of q,k (per batch [S,E] -> [E,S]) ----
  transp_bf16_k<<<dim3(E_ / 32, S_ / 32, B_), blk32x8, 0, stream>>>(qb, qT, S_, E_);
  transp_bf16_k<<<dim3(E_ / 32, S_ / 32, B_), blk32x8, 0, stream>>>(kb, kT, S_, E_);

  // ---- logits = q k^T / 32 -> Fout; softmax in place + fb ----
  gemm(qb, kb, S_, S_, E_, (long)S_ * E_, (long)S_ * E_, (long)S_ * S_, B_,
       1.f / 32.f, 0, nullptr, 0, nullptr, 0, Fout, nullptr);
  softmax_row_k<<<dim3(S_, B_), blk256, 0, stream>>>(Fout, fb);

  // ---- colsum(k) ----
  colsum_part_k<<<dim3(E_ / 256, 8, B_), blk256, 0, stream>>>(kb, part);
  colsum_fin_k<<<dim3(E_ / 256, B_), blk256, 0, stream>>>(part, ck);

  // ---- vq = q v^T / 32 ; vk = k v^T / 32 (bf16, padded N=64) ----
  gemm(qb, vb, S_, SVP_, E_, (long)S_ * E_, (long)SVP_ * E_, (long)S_ * SVP_, B_,
       1.f / 32.f, 0, nullptr, 0, nullptr, 0, nullptr, vqf);
  gemm(kb, vb, S_, SVP_, E_, (long)S_ * E_, (long)SVP_ * E_, (long)S_ * SVP_, B_,
       1.f / 32.f, 0, nullptr, 0, nullptr, 0, nullptr, vkf);

  // ---- q2 = f@q + vq@W_vq ----
  gemm(vqf, WvqT, B_ * S_, E_, SVP_, 0, 0, 0, 1, 1.f, 0, nullptr, 0, nullptr, 0,
       nullptr, Tmp);
  gemm(fb, qT, S_, E_, S_, (long)S_ * S_, (long)E_ * S_, (long)S_ * E_, B_, 1.f, 0,
       Tmp, (long)S_ * E_, nullptr, 0, nullptr, q2);

  // ---- k2 = colsum(k) - f@k + vk@W_vk ----
  gemm(vkf, WvkT, B_ * S_, E_, SVP_, 0, 0, 0, 1, 1.f, 0, nullptr, 0, nullptr, 0,
       nullptr, Tmp);
  gemm(fb, kT, S_, E_, S_, (long)S_ * S_, (long)E_ * S_, (long)S_ * E_, B_, 1.f, 1,
       Tmp, (long)S_ * E_, ck, E_, nullptr, k2);

  // ---- transposes of q2,k2 ----
  transp_bf16_k<<<dim3(E_ / 32, S_ / 32, B_), blk32x8, 0, stream>>>(q2, q2T, S_, E_);
  transp_bf16_k<<<dim3(E_ / 32, S_ / 32, B_), blk32x8, 0, stream>>>(k2, k2T, S_, E_);

  // ---- colsum(k2) ----
  colsum_part_k<<<dim3(E_ / 256, 8, B_), blk256, 0, stream>>>(k2, part);
  colsum_fin_k<<<dim3(E_ / 256, B_), blk256, 0, stream>>>(part, ck2);

  // ---- Q_out = f@q2 ; K_out = colsum(k2) - f@k2 ----
  gemm(fb, q2T, S_, E_, S_, (long)S_ * S_, (long)E_ * S_, (long)S_ * E_, B_, 1.f, 0,
       nullptr, 0, nullptr, 0, Qout, nullptr);
  gemm(fb, k2T, S_, E_, S_, (long)S_ * S_, (long)E_ * S_, (long)S_ * E_, B_, 1.f, 1,
       nullptr, 0, ck2, E_, Kout, nullptr);
}

// Round 2
// 745.691 us; speedup vs baseline: 1.4667x; 1.4667x over previous
//
#include <hip/hip_runtime.h>
#include <cstdint>
#include <cstddef>

typedef __bf16 bf16_t;
typedef __bf16 bf16x8 __attribute__((ext_vector_type(8)));
typedef float floatx4 __attribute__((ext_vector_type(4)));

#define B_ 4
#define S_ 2048
#define E_ 1024
#define SV_ 50
#define SVP_ 64

__device__ __forceinline__ void async_copy16(const bf16_t* g, bf16_t* l) {
  __builtin_amdgcn_global_load_lds(
      (const __attribute__((address_space(1))) void*)g,
      (__attribute__((address_space(3))) void*)l, 16, 0, 0);
}

// ---------------- elementwise tanh + cast ----------------
__global__ __launch_bounds__(256) void tanh_cast_k(const float* __restrict__ in,
                                                   bf16_t* __restrict__ out, long n) {
  long i = (long)blockIdx.x * 256 + threadIdx.x;
  if (i < n) out[i] = (bf16_t)tanhf(in[i]);
}

// V [B,50,1024] -> tanh, padded to [B,64,1024] with zero rows
__global__ __launch_bounds__(256) void tanh_vpad_k(const float* __restrict__ V,
                                                   bf16_t* __restrict__ out) {
  int i = blockIdx.x * 256 + threadIdx.x;  // covers B*64*1024
  int e = i & 1023, r = (i >> 10) & 63, b = i >> 16;
  float v = 0.f;
  if (r < SV_) v = tanhf(V[((long)(b * SV_ + r) << 10) + e]);
  out[i] = (bf16_t)v;
}

// ---------------- W [K,N] fp32 -> Wt [N,Kp] bf16 (zero-pad k>=K) ----------------
__global__ __launch_bounds__(256) void transp_cast_k(const float* __restrict__ W,
                                                     bf16_t* __restrict__ out,
                                                     int K, int N, int Kp) {
  __shared__ float tile[32][33];
  int k0 = blockIdx.y * 32, n0 = blockIdx.x * 32;
  int tx = threadIdx.x, ty = threadIdx.y;  // block (32,8)
#pragma unroll
  for (int s2 = 0; s2 < 4; ++s2) {
    int kk = ty + s2 * 8;
    float v = 0.f;
    if (k0 + kk < K && n0 + tx < N) v = W[(long)(k0 + kk) * N + n0 + tx];
    tile[kk][tx] = v;
  }
  __syncthreads();
#pragma unroll
  for (int s2 = 0; s2 < 4; ++s2) {
    int nn = ty + s2 * 8;
    if (n0 + nn < N && k0 + tx < Kp)
      out[(long)(n0 + nn) * Kp + k0 + tx] = (bf16_t)tile[tx][nn];
  }
}

// ---------------- per-batch bf16 transpose [R,C] -> [C,R] ----------------
__global__ __launch_bounds__(256) void transp_bf16_k(const bf16_t* __restrict__ in,
                                                     bf16_t* __restrict__ out,
                                                     int R, int C) {
  __shared__ bf16_t tile[32][33];
  long boff = (long)blockIdx.z * R * C;
  int r0 = blockIdx.y * 32, c0 = blockIdx.x * 32;
  int tx = threadIdx.x, ty = threadIdx.y;  // block (32,8)
#pragma unroll
  for (int s2 = 0; s2 < 4; ++s2)
    tile[ty + s2 * 8][tx] = in[boff + (long)(r0 + ty + s2 * 8) * C + c0 + tx];
  __syncthreads();
#pragma unroll
  for (int s2 = 0; s2 < 4; ++s2)
    out[boff + (long)(c0 + ty + s2 * 8) * R + r0 + tx] = tile[tx][ty + s2 * 8];
}

// ---------------- column-sum over t of bf16 [B,S,E] -> fp32 [B,E] ----------------
__global__ __launch_bounds__(256) void colsum_part_k(const bf16_t* __restrict__ X,
                                                     float* __restrict__ part) {
  // grid (E/256, 8, B); part [B][8][E]
  int e = blockIdx.x * 256 + threadIdx.x;
  int chunk = blockIdx.y, b = blockIdx.z;
  const bf16_t* p = X + ((long)b * S_ + (long)chunk * 256) * E_ + e;
  float s = 0.f;
#pragma unroll 8
  for (int t = 0; t < 256; ++t) s += (float)p[(long)t * E_];
  part[((long)b * 8 + chunk) * E_ + e] = s;
}

__global__ __launch_bounds__(256) void colsum_fin_k(const float* __restrict__ part,
                                                    float* __restrict__ out) {
  // grid (E/256, B)
  int e = blockIdx.x * 256 + threadIdx.x;
  int b = blockIdx.y;
  float s = 0.f;
#pragma unroll
  for (int c = 0; c < 8; ++c) s += part[((long)b * 8 + c) * E_ + e];
  out[(long)b * E_ + e] = s;
}

// ---------------- row softmax (in-place on fp32 logits) + bf16 copy ----------------
__global__ __launch_bounds__(256) void softmax_row_k(float* __restrict__ logits,
                                                     bf16_t* __restrict__ fb) {
  long off = ((long)blockIdx.y * S_ + blockIdx.x) * S_;
  float* p = logits + off;
  bf16_t* pb = fb + off;
  int t = threadIdx.x;
  float x[8];
  float mx = -3.4e38f;
#pragma unroll
  for (int i = 0; i < 8; ++i) {
    x[i] = p[t + 256 * i];
    mx = fmaxf(mx, x[i]);
  }
  __shared__ float red[256];
  red[t] = mx;
  __syncthreads();
#pragma unroll
  for (int s = 128; s >= 1; s >>= 1) {
    if (t < s) red[t] = fmaxf(red[t], red[t + s]);
    __syncthreads();
  }
  mx = red[0];
  __syncthreads();
  float sum = 0.f;
#pragma unroll
  for (int i = 0; i < 8; ++i) {
    x[i] = __expf(x[i] - mx);
    sum += x[i];
  }
  red[t] = sum;
  __syncthreads();
#pragma unroll
  for (int s = 128; s >= 1; s >>= 1) {
    if (t < s) red[t] += red[t + s];
    __syncthreads();
  }
  float inv = 1.0f / red[0];
#pragma unroll
  for (int i = 0; i < 8; ++i) {
    float v = x[i] * inv;
    p[t + 256 * i] = v;
    pb[t + 256 * i] = (bf16_t)v;
  }
}

// ---------------- small NT GEMM (64x64 tile) for N==64 cases ----------------
__global__ __launch_bounds__(256) void gemm_nt_k(
    const bf16_t* __restrict__ A, const bf16_t* __restrict__ B,
    int N, int K, long sA, long sB, long sO, long sC, long sV,
    float alpha, int negAcc,
    const bf16_t* __restrict__ Cadd, const float* __restrict__ colVec,
    float* __restrict__ outF, bf16_t* __restrict__ outB) {
  __shared__ __align__(16) bf16_t As[64 * 64];
  __shared__ __align__(16) bf16_t Bs[64 * 64];
  const int t = threadIdx.x;
  const int lane = t & 63;
  const int wave = t >> 6;
  const int wm = (wave & 1) * 32;
  const int wn = (wave >> 1) * 32;
  const long b = blockIdx.z;
  const bf16_t* Ab = A + b * sA;
  const bf16_t* Bb = B + b * sB;
  const long rowBase = (long)blockIdx.y * 64;
  const long colBase = (long)blockIdx.x * 64;

  floatx4 acc[2][2];
#pragma unroll
  for (int i = 0; i < 2; ++i)
#pragma unroll
    for (int j = 0; j < 2; ++j) acc[i][j] = {0.f, 0.f, 0.f, 0.f};

  const int sr = t >> 3;       // staging row 0..31
  const int sc = (t & 7) * 8;  // staging col element 0..56 (16B chunks)
  for (int k0 = 0; k0 < K; k0 += 64) {
#pragma unroll
    for (int p = 0; p < 2; ++p) {
      int r = p * 32 + sr;
      *(uint4*)&As[r * 64 + sc] = *(const uint4*)&Ab[(rowBase + r) * K + k0 + sc];
      *(uint4*)&Bs[r * 64 + sc] = *(const uint4*)&Bb[(colBase + r) * K + k0 + sc];
    }
    __syncthreads();
#pragma unroll
    for (int ks = 0; ks < 64; ks += 32) {
      const int fr = lane & 15;
      const int fk = ks + ((lane >> 4) << 3);
      bf16x8 a0 = *(const bf16x8*)&As[(wm + fr) * 64 + fk];
      bf16x8 a1 = *(const bf16x8*)&As[(wm + 16 + fr) * 64 + fk];
      bf16x8 b0 = *(const bf16x8*)&Bs[(wn + fr) * 64 + fk];
      bf16x8 b1 = *(const bf16x8*)&Bs[(wn + 16 + fr) * 64 + fk];
      acc[0][0] = __builtin_amdgcn_mfma_f32_16x16x32_bf16(a0, b0, acc[0][0], 0, 0, 0);
      acc[0][1] = __builtin_amdgcn_mfma_f32_16x16x32_bf16(a0, b1, acc[0][1], 0, 0, 0);
      acc[1][0] = __builtin_amdgcn_mfma_f32_16x16x32_bf16(a1, b0, acc[1][0], 0, 0, 0);
      acc[1][1] = __builtin_amdgcn_mfma_f32_16x16x32_bf16(a1, b1, acc[1][1], 0, 0, 0);
    }
    __syncthreads();
  }

  const int cr = lane & 15;
  const int rq = (lane >> 4) * 4;
#pragma unroll
  for (int i = 0; i < 2; ++i)
#pragma unroll
    for (int j = 0; j < 2; ++j)
#pragma unroll
      for (int r = 0; r < 4; ++r) {
        long row = rowBase + wm + i * 16 + rq + r;
        long col = colBase + wn + j * 16 + cr;
        float v = alpha * acc[i][j][r];
        if (negAcc) v = -v;
        if (Cadd) v += (float)Cadd[b * sC + row * N + col];
        if (colVec) v += colVec[b * sV + col];
        long o = b * sO + row * N + col;
        if (outF) outF[o] = v;
        if (outB) outB[o] = (bf16_t)v;
      }
}

// ---------------- m97-style 128x128 NT GEMM, global_load_lds + XOR swizzle -------
// A: [M,K] row-major; B: [N,K] row-major. M%128==0, N%128==0, K%64==0.
// LDS slot (row, chunk c) holds global k-chunk c^(row&7)  (chunk = 8 bf16 = 16B).
__global__ __launch_bounds__(256) void gemm128_k(
    const bf16_t* __restrict__ A, const bf16_t* __restrict__ B,
    int N, int K, long sA, long sB, long sO, long sC, long sV,
    float alpha, int negAcc,
    const bf16_t* __restrict__ Cadd, const float* __restrict__ colVec,
    float* __restrict__ outF, bf16_t* __restrict__ outB) {
  __shared__ __align__(16) bf16_t As[128 * 64];
  __shared__ __align__(16) bf16_t Bs[128 * 64];
  const int t = threadIdx.x;
  const int lane = t & 63;
  const int wave = t >> 6;
  const int wm = (wave & 1) * 64;   // wave row offset in tile
  const int wn = (wave >> 1) * 64;  // wave col offset in tile
  const long b = blockIdx.z;
  const bf16_t* Ab = A + b * sA;
  const bf16_t* Bb = B + b * sB;
  const long rowBase = (long)blockIdx.y * 128;
  const long colBase = (long)blockIdx.x * 128;

  floatx4 acc[4][4];
#pragma unroll
  for (int i = 0; i < 4; ++i)
#pragma unroll
    for (int j = 0; j < 4; ++j) acc[i][j] = {0.f, 0.f, 0.f, 0.f};

  // ---- staging setup: each wave DMAs rows [wave*32, wave*32+32) of As and Bs ----
  const int srow = lane >> 3;                 // 0..7 within an 8-row group
  const int schunk = (lane & 7) ^ srow;       // swizzled k-chunk this lane fetches
  const bf16_t* aG[4];
  const bf16_t* bG[4];
  bf16_t* aL[4];
  bf16_t* bL[4];
#pragma unroll
  for (int i = 0; i < 4; ++i) {
    int r = wave * 32 + i * 8;  // group base row in tile
    aG[i] = Ab + (rowBase + r + srow) * (long)K + schunk * 8;
    bG[i] = Bb + (colBase + r + srow) * (long)K + schunk * 8;
    aL[i] = &As[r * 64];  // wave-uniform LDS base; HW writes base + lane*16B
    bL[i] = &Bs[r * 64];
  }

  // ---- fragment read offsets (element units), with swizzle baked in ----
  const int fr = lane & 15;
  const int hi = lane >> 4;  // 0..3
  int aoff[4], boff[4];
#pragma unroll
  for (int i = 0; i < 4; ++i) {
    aoff[i] = (wm + i * 16 + fr) * 64 + ((hi ^ (fr & 7)) * 8);
    boff[i] = (wn + i * 16 + fr) * 64 + ((hi ^ (fr & 7)) * 8);
  }

  for (int k0 = 0; k0 < K; k0 += 64) {
#pragma unroll
    for (int i = 0; i < 4; ++i) {
      async_copy16(aG[i] + k0, aL[i]);
      async_copy16(bG[i] + k0, bL[i]);
    }
    __syncthreads();  // drains vmcnt (global_load_lds) before any wave reads LDS
#pragma unroll
    for (int ks = 0; ks < 64; ks += 32) {
      bf16x8 af[4], bf[4];
#pragma unroll
      for (int i = 0; i < 4; ++i) af[i] = *(const bf16x8*)&As[aoff[i] ^ ks];
#pragma unroll
      for (int i = 0; i < 4; ++i) bf[i] = *(const bf16x8*)&Bs[boff[i] ^ ks];
#pragma unroll
      for (int i = 0; i < 4; ++i)
#pragma unroll
        for (int j = 0; j < 4; ++j)
          acc[i][j] =
              __builtin_amdgcn_mfma_f32_16x16x32_bf16(af[i], bf[j], acc[i][j], 0, 0, 0);
    }
    __syncthreads();
  }

  const int cr = lane & 15;
  const int rq = hi * 4;
#pragma unroll
  for (int i = 0; i < 4; ++i)
#pragma unroll
    for (int j = 0; j < 4; ++j)
#pragma unroll
      for (int r = 0; r < 4; ++r) {
        long row = rowBase + wm + i * 16 + rq + r;
        long col = colBase + wn + j * 16 + cr;
        float v = alpha * acc[i][j][r];
        if (negAcc) v = -v;
        if (Cadd) v += (float)Cadd[b * sC + row * N + col];
        if (colVec) v += colVec[b * sV + col];
        long o = b * sO + row * N + col;
        if (outF) outF[o] = v;
        if (outB) outB[o] = (bf16_t)v;
      }
}

extern "C" void kernel_launch(void* const* d_in, const int* in_sizes, int n_in,
                              void* d_out, int out_size, void* d_ws, size_t ws_size,
                              hipStream_t stream) {
  const float* Q = (const float*)d_in[0];
  const float* Kin = (const float*)d_in[1];
  const float* V = (const float*)d_in[2];
  const float* W_Q = (const float*)d_in[3];
  const float* W_K = (const float*)d_in[4];
  const float* W_v = (const float*)d_in[5];
  const float* W_vq = (const float*)d_in[6];
  const float* W_vk = (const float*)d_in[7];

  float* Qout = (float*)d_out;                  // [4,2048,1024]
  float* Kout = Qout + (long)B_ * S_ * E_;      // [4,2048,1024]
  float* Fout = Kout + (long)B_ * S_ * E_;      // [4,2048,2048] (also logits scratch)

  char* w = (char*)d_ws;
  auto alloc = [&](size_t bytes) {
    char* p = w;
    w += (bytes + 255) & ~(size_t)255;
    return p;
  };
  bf16_t* WQt = (bf16_t*)alloc((size_t)2 * E_ * E_);
  bf16_t* WKt = (bf16_t*)alloc((size_t)2 * E_ * E_);
  bf16_t* WVt = (bf16_t*)alloc((size_t)2 * E_ * E_);
  bf16_t* WvqT = (bf16_t*)alloc((size_t)2 * E_ * SVP_);
  bf16_t* WvkT = (bf16_t*)alloc((size_t)2 * E_ * SVP_);
  bf16_t* Qt = (bf16_t*)alloc((size_t)2 * B_ * S_ * E_);  // later reused as q2
  bf16_t* Kt = (bf16_t*)alloc((size_t)2 * B_ * S_ * E_);  // later reused as k2
  bf16_t* Vt = (bf16_t*)alloc((size_t)2 * B_ * SVP_ * E_);
  bf16_t* qb = (bf16_t*)alloc((size_t)2 * B_ * S_ * E_);  // later reused as q2T
  bf16_t* kb = (bf16_t*)alloc((size_t)2 * B_ * S_ * E_);  // later reused as k2T
  bf16_t* vb = (bf16_t*)alloc((size_t)2 * B_ * SVP_ * E_);
  bf16_t* qT = (bf16_t*)alloc((size_t)2 * B_ * S_ * E_);
  bf16_t* kT = (bf16_t*)alloc((size_t)2 * B_ * S_ * E_);
  bf16_t* fb = (bf16_t*)alloc((size_t)2 * B_ * S_ * S_);
  bf16_t* vqf = (bf16_t*)alloc((size_t)2 * B_ * S_ * SVP_);
  bf16_t* vkf = (bf16_t*)alloc((size_t)2 * B_ * S_ * SVP_);
  bf16_t* Tmp = (bf16_t*)alloc((size_t)2 * B_ * S_ * E_);
  float* part = (float*)alloc((size_t)4 * B_ * 8 * E_);
  float* ck = (float*)alloc((size_t)4 * B_ * E_);
  float* ck2 = (float*)alloc((size_t)4 * B_ * E_);
  bf16_t* q2 = Qt;
  bf16_t* k2 = Kt;
  bf16_t* q2T = qb;
  bf16_t* k2T = kb;

  dim3 blk256(256);
  dim3 blk32x8(32, 8);

  // small-N (N==64) path
  auto gemm64 = [&](const bf16_t* A, const bf16_t* Bp, int M, int N, int K,
                    long sA, long sB, long sO, int nb, float alpha, int negAcc,
                    const bf16_t* Cadd, long sC, const float* colVec, long sV,
                    float* outF, bf16_t* outB) {
    gemm_nt_k<<<dim3(N / 64, M / 64, nb), dim3(256), 0, stream>>>(
        A, Bp, N, K, sA, sB, sO, sC, sV, alpha, negAcc, Cadd, colVec, outF, outB);
  };
  // heavy path: 128x128 tile
  auto gemm = [&](const bf16_t* A, const bf16_t* Bp, int M, int N, int K,
                  long sA, long sB, long sO, int nb, float alpha, int negAcc,
                  const bf16_t* Cadd, long sC, const float* colVec, long sV,
                  float* outF, bf16_t* outB) {
    gemm128_k<<<dim3(N / 128, M / 128, nb), dim3(256), 0, stream>>>(
        A, Bp, N, K, sA, sB, sO, sC, sV, alpha, negAcc, Cadd, colVec, outF, outB);
  };

  // ---- weight prep: W[K,N] fp32 -> [N,Kp] bf16 ----
  transp_cast_k<<<dim3(32, 32), blk32x8, 0, stream>>>(W_Q, WQt, E_, E_, E_);
  transp_cast_k<<<dim3(32, 32), blk32x8, 0, stream>>>(W_K, WKt, E_, E_, E_);
  transp_cast_k<<<dim3(32, 32), blk32x8, 0, stream>>>(W_v, WVt, E_, E_, E_);
  transp_cast_k<<<dim3(32, 2), blk32x8, 0, stream>>>(W_vq, WvqT, SV_, E_, SVP_);
  transp_cast_k<<<dim3(32, 2), blk32x8, 0, stream>>>(W_vk, WvkT, SV_, E_, SVP_);

  // ---- tanh + cast inputs ----
  long nQ = (long)B_ * S_ * E_;
  tanh_cast_k<<<dim3((unsigned)(nQ / 256)), blk256, 0, stream>>>(Q, Qt, nQ);
  tanh_cast_k<<<dim3((unsigned)(nQ / 256)), blk256, 0, stream>>>(Kin, Kt, nQ);
  tanh_vpad_k<<<dim3(B_ * SVP_ * E_ / 256), blk256, 0, stream>>>(V, Vt);

  // ---- projections (flat over B*S) ----
  gemm(Qt, WQt, B_ * S_, E_, E_, 0, 0, 0, 1, 1.f, 0, nullptr, 0, nullptr, 0, nullptr, qb);
  gemm(Kt, WKt, B_ * S_, E_, E_, 0, 0, 0, 1, 1.f, 0, nullptr, 0, nullptr, 0, nullptr, kb);
  gemm(Vt, WVt, B_ * SVP_, E_, E_, 0, 0, 0, 1, 1.f, 0, nullptr, 0, nullptr, 0, nullptr, vb);

  // ---- transposes of q,k (per batch [S,E] -> [E,S]) ----
  transp_bf16_k<<<dim3(E_ / 32, S_ / 32, B_), blk32x8, 0, stream>>>(qb, qT, S_, E_);
  transp_bf16_k<<<dim3(E_ / 32, S_ / 32, B_), blk32x8, 0, stream>>>(kb, kT, S_, E_);

  // ---- logits = q k^T / 32 -> Fout; softmax in place + fb ----
  gemm(qb, kb, S_, S_, E_, (long)S_ * E_, (long)S_ * E_, (long)S_ * S_, B_,
       1.f / 32.f, 0, nullptr, 0, nullptr, 0, Fout, nullptr);
  softmax_row_k<<<dim3(S_, B_), blk256, 0, stream>>>(Fout, fb);

  // ---- colsum(k) ----
  colsum_part_k<<<dim3(E_ / 256, 8, B_), blk256, 0, stream>>>(kb, part);
  colsum_fin_k<<<dim3(E_ / 256, B_), blk256, 0, stream>>>(part, ck);

  // ---- vq = q v^T / 32 ; vk = k v^T / 32 (bf16, padded N=64) ----
  gemm64(qb, vb, S_, SVP_, E_, (long)S_ * E_, (long)SVP_ * E_, (long)S_ * SVP_, B_,
         1.f / 32.f, 0, nullptr, 0, nullptr, 0, nullptr, vqf);
  gemm64(kb, vb, S_, SVP_, E_, (long)S_ * E_, (long)SVP_ * E_, (long)S_ * SVP_, B_,
         1.f / 32.f, 0, nullptr, 0, nullptr, 0, nullptr, vkf);

  // ---- q2 = f@q + vq@W_vq ----
  gemm(vqf, WvqT, B_ * S_, E_, SVP_, 0, 0, 0, 1, 1.f, 0, nullptr, 0, nullptr, 0,
       nullptr, Tmp);
  gemm(fb, qT, S_, E_, S_, (long)S_ * S_, (long)E_ * S_, (long)S_ * E_, B_, 1.f, 0,
       Tmp, (long)S_ * E_, nullptr, 0, nullptr, q2);

  // ---- k2 = colsum(k) - f@k + vk@W_vk ----
  gemm(vkf, WvkT, B_ * S_, E_, SVP_, 0, 0, 0, 1, 1.f, 0, nullptr, 0, nullptr, 0,
       nullptr, Tmp);
  gemm(fb, kT, S_, E_, S_, (long)S_ * S_, (long)E_ * S_, (long)S_ * E_, B_, 1.f, 1,
       Tmp, (long)S_ * E_, ck, E_, nullptr, k2);

  // ---- transposes of q2,k2 ----
  transp_bf16_k<<<dim3(E_ / 32, S_ / 32, B_), blk32x8, 0, stream>>>(q2, q2T, S_, E_);
  transp_bf16_k<<<dim3(E_ / 32, S_ / 32, B_), blk32x8, 0, stream>>>(k2, k2T, S_, E_);

  // ---- colsum(k2) ----
  colsum_part_k<<<dim3(E_ / 256, 8, B_), blk256, 0, stream>>>(k2, part);
  colsum_fin_k<<<dim3(E_ / 256, B_), blk256, 0, stream>>>(part, ck2);

  // ---- Q_out = f@q2 ; K_out = colsum(k2) - f@k2 ----
  gemm(fb, q2T, S_, E_, S_, (long)S_ * S_, (long)E_ * S_, (long)S_ * E_, B_, 1.f, 0,
       nullptr, 0, nullptr, 0, Qout, nullptr);
  gemm(fb, k2T, S_, E_, S_, (long)S_ * S_, (long)E_ * S_, (long)S_ * E_, B_, 1.f, 1,
       nullptr, 0, ck2, E_, Kout, nullptr);
}

// Round 3
// 684.327 us; speedup vs baseline: 1.5982x; 1.0897x over previous
//
#include <hip/hip_runtime.h>
#include <cstdint>
#include <cstddef>

typedef __bf16 bf16_t;
typedef __bf16 bf16x4 __attribute__((ext_vector_type(4)));
typedef __bf16 bf16x8 __attribute__((ext_vector_type(8)));
typedef float floatx4 __attribute__((ext_vector_type(4)));

#define B_ 4
#define S_ 2048
#define E_ 1024
#define SV_ 50
#define SVP_ 64

__device__ __forceinline__ void async_copy16(const bf16_t* g, bf16_t* l) {
  __builtin_amdgcn_global_load_lds(
      (const __attribute__((address_space(1))) void*)g,
      (__attribute__((address_space(3))) void*)l, 16, 0, 0);
}

// ---------------- tanh of Q and K (concat), float4 vectorized ----------------
__global__ __launch_bounds__(256) void tanh2_k(const float* __restrict__ Q,
                                               const float* __restrict__ Kin,
                                               bf16_t* __restrict__ out) {
  long i4 = ((long)blockIdx.x * 256 + threadIdx.x) * 4;
  const long n = (long)B_ * S_ * E_;
  const float* src = (i4 < n) ? (Q + i4) : (Kin + (i4 - n));
  float4 x = *(const float4*)src;
  bf16x4 o;
  o[0] = (bf16_t)tanhf(x.x);
  o[1] = (bf16_t)tanhf(x.y);
  o[2] = (bf16_t)tanhf(x.z);
  o[3] = (bf16_t)tanhf(x.w);
  *(bf16x4*)&out[i4] = o;
}

// V [B,50,1024] -> tanh, padded to [B,64,1024] with zero rows
__global__ __launch_bounds__(256) void tanh_vpad_k(const float* __restrict__ V,
                                                   bf16_t* __restrict__ out) {
  int i = blockIdx.x * 256 + threadIdx.x;  // covers B*64*1024
  int e = i & 1023, r = (i >> 10) & 63, b = i >> 16;
  float v = 0.f;
  if (r < SV_) v = tanhf(V[((long)(b * SV_ + r) << 10) + e]);
  out[i] = (bf16_t)v;
}

// ---------------- W [K,N] fp32 -> Wt [N,Kp] bf16 (zero-pad k>=K) ----------------
__global__ __launch_bounds__(256) void transp_cast_k(const float* __restrict__ W,
                                                     bf16_t* __restrict__ out,
                                                     int K, int N, int Kp) {
  __shared__ float tile[32][33];
  int k0 = blockIdx.y * 32, n0 = blockIdx.x * 32;
  int tx = threadIdx.x, ty = threadIdx.y;  // block (32,8)
#pragma unroll
  for (int s2 = 0; s2 < 4; ++s2) {
    int kk = ty + s2 * 8;
    float v = 0.f;
    if (k0 + kk < K && n0 + tx < N) v = W[(long)(k0 + kk) * N + n0 + tx];
    tile[kk][tx] = v;
  }
  __syncthreads();
#pragma unroll
  for (int s2 = 0; s2 < 4; ++s2) {
    int nn = ty + s2 * 8;
    if (n0 + nn < N && k0 + tx < Kp)
      out[(long)(n0 + nn) * Kp + k0 + tx] = (bf16_t)tile[tx][nn];
  }
}

// ---------------- strided bf16 transpose: out[c][r] = in[r][c] ----------------
__global__ __launch_bounds__(256) void transp_bf16_k(const bf16_t* __restrict__ in,
                                                     long inRow, long inBatch,
                                                     bf16_t* __restrict__ out,
                                                     long outRow, long outBatch) {
  __shared__ bf16_t tile[32][33];
  int r0 = blockIdx.y * 32, c0 = blockIdx.x * 32;
  int tx = threadIdx.x, ty = threadIdx.y;  // block (32,8)
  long ib = (long)blockIdx.z * inBatch;
  long ob = (long)blockIdx.z * outBatch;
#pragma unroll
  for (int s2 = 0; s2 < 4; ++s2)
    tile[ty + s2 * 8][tx] = in[ib + (long)(r0 + ty + s2 * 8) * inRow + c0 + tx];
  __syncthreads();
#pragma unroll
  for (int s2 = 0; s2 < 4; ++s2)
    out[ob + (long)(c0 + ty + s2 * 8) * outRow + r0 + tx] = tile[tx][ty + s2 * 8];
}

// ---------------- strided column-sum over 2048 rows -> fp32 [B,E] ----------------
__global__ __launch_bounds__(256) void colsum_part_k(const bf16_t* __restrict__ X,
                                                     long rowStride, long batchStride,
                                                     float* __restrict__ part) {
  // grid (E/256, 8, B); part [B][8][E]
  int e = blockIdx.x * 256 + threadIdx.x;
  int chunk = blockIdx.y, b = blockIdx.z;
  const bf16_t* p = X + (long)b * batchStride + (long)chunk * 256 * rowStride + e;
  float s = 0.f;
#pragma unroll 8
  for (int t = 0; t < 256; ++t) s += (float)p[(long)t * rowStride];
  part[((long)b * 8 + chunk) * E_ + e] = s;
}

__global__ __launch_bounds__(256) void colsum_fin_k(const float* __restrict__ part,
                                                    float* __restrict__ out) {
  // grid (E/256, B)
  int e = blockIdx.x * 256 + threadIdx.x;
  int b = blockIdx.y;
  float s = 0.f;
#pragma unroll
  for (int c = 0; c < 8; ++c) s += part[((long)b * 8 + c) * E_ + e];
  out[(long)b * E_ + e] = s;
}

// ---------------- row softmax (in-place fp32) + bf16 copy, vectorized ----------
__global__ __launch_bounds__(256) void softmax_row_k(float* __restrict__ logits,
                                                     bf16_t* __restrict__ fb) {
  long off = ((long)blockIdx.y * S_ + blockIdx.x) * S_;
  float* p = logits + off;
  int t = threadIdx.x;
  float4 x0 = *(float4*)&p[8 * t];
  float4 x1 = *(float4*)&p[8 * t + 4];
  float mx = fmaxf(fmaxf(fmaxf(x0.x, x0.y), fmaxf(x0.z, x0.w)),
                   fmaxf(fmaxf(x1.x, x1.y), fmaxf(x1.z, x1.w)));
#pragma unroll
  for (int s = 32; s >= 1; s >>= 1) mx = fmaxf(mx, __shfl_xor(mx, s));
  __shared__ float red[4];
  int wv = t >> 6;
  if ((t & 63) == 0) red[wv] = mx;
  __syncthreads();
  mx = fmaxf(fmaxf(red[0], red[1]), fmaxf(red[2], red[3]));
  float e0 = __expf(x0.x - mx), e1 = __expf(x0.y - mx), e2 = __expf(x0.z - mx),
        e3 = __expf(x0.w - mx);
  float e4 = __expf(x1.x - mx), e5 = __expf(x1.y - mx), e6 = __expf(x1.z - mx),
        e7 = __expf(x1.w - mx);
  float sum = (e0 + e1) + (e2 + e3) + (e4 + e5) + (e6 + e7);
#pragma unroll
  for (int s = 32; s >= 1; s >>= 1) sum += __shfl_xor(sum, s);
  __shared__ float red2[4];
  if ((t & 63) == 0) red2[wv] = sum;
  __syncthreads();
  float inv = 1.0f / ((red2[0] + red2[1]) + (red2[2] + red2[3]));
  e0 *= inv; e1 *= inv; e2 *= inv; e3 *= inv;
  e4 *= inv; e5 *= inv; e6 *= inv; e7 *= inv;
  *(float4*)&p[8 * t] = make_float4(e0, e1, e2, e3);
  *(float4*)&p[8 * t + 4] = make_float4(e4, e5, e6, e7);
  bf16x8 ob;
  ob[0] = (bf16_t)e0; ob[1] = (bf16_t)e1; ob[2] = (bf16_t)e2; ob[3] = (bf16_t)e3;
  ob[4] = (bf16_t)e4; ob[5] = (bf16_t)e5; ob[6] = (bf16_t)e6; ob[7] = (bf16_t)e7;
  *(bf16x8*)&fb[off + 8 * t] = ob;
}

// ---------------- small NT GEMM (64x64 tile) for N==64 (vq/vk) ----------------
__global__ __launch_bounds__(256) void gemm_nt_k(
    const bf16_t* __restrict__ A, const bf16_t* __restrict__ B,
    int N, int K, long sA, long sB, long sO,
    float alpha, int negAcc, bf16_t* __restrict__ outB) {
  __shared__ __align__(16) bf16_t As[64 * 64];
  __shared__ __align__(16) bf16_t Bs[64 * 64];
  const int t = threadIdx.x;
  const int lane = t & 63;
  const int wave = t >> 6;
  const int wm = (wave & 1) * 32;
  const int wn = (wave >> 1) * 32;
  const long b = blockIdx.z;
  const bf16_t* Ab = A + b * sA;
  const bf16_t* Bb = B + b * sB;
  const long rowBase = (long)blockIdx.y * 64;
  const long colBase = (long)blockIdx.x * 64;

  floatx4 acc[2][2];
#pragma unroll
  for (int i = 0; i < 2; ++i)
#pragma unroll
    for (int j = 0; j < 2; ++j) acc[i][j] = {0.f, 0.f, 0.f, 0.f};

  const int sr = t >> 3;
  const int sc = (t & 7) * 8;
  for (int k0 = 0; k0 < K; k0 += 64) {
#pragma unroll
    for (int p = 0; p < 2; ++p) {
      int r = p * 32 + sr;
      *(uint4*)&As[r * 64 + sc] = *(const uint4*)&Ab[(rowBase + r) * K + k0 + sc];
      *(uint4*)&Bs[r * 64 + sc] = *(const uint4*)&Bb[(colBase + r) * K + k0 + sc];
    }
    __syncthreads();
#pragma unroll
    for (int ks = 0; ks < 64; ks += 32) {
      const int fr = lane & 15;
      const int fk = ks + ((lane >> 4) << 3);
      bf16x8 a0 = *(const bf16x8*)&As[(wm + fr) * 64 + fk];
      bf16x8 a1 = *(const bf16x8*)&As[(wm + 16 + fr) * 64 + fk];
      bf16x8 b0 = *(const bf16x8*)&Bs[(wn + fr) * 64 + fk];
      bf16x8 b1 = *(const bf16x8*)&Bs[(wn + 16 + fr) * 64 + fk];
      acc[0][0] = __builtin_amdgcn_mfma_f32_16x16x32_bf16(a0, b0, acc[0][0], 0, 0, 0);
      acc[0][1] = __builtin_amdgcn_mfma_f32_16x16x32_bf16(a0, b1, acc[0][1], 0, 0, 0);
      acc[1][0] = __builtin_amdgcn_mfma_f32_16x16x32_bf16(a1, b0, acc[1][0], 0, 0, 0);
      acc[1][1] = __builtin_amdgcn_mfma_f32_16x16x32_bf16(a1, b1, acc[1][1], 0, 0, 0);
    }
    __syncthreads();
  }

  const int cr = lane & 15;
  const int rq = (lane >> 4) * 4;
#pragma unroll
  for (int i = 0; i < 2; ++i)
#pragma unroll
    for (int j = 0; j < 2; ++j)
#pragma unroll
      for (int r = 0; r < 4; ++r) {
        long row = rowBase + wm + i * 16 + rq + r;
        long col = colBase + wn + j * 16 + cr;
        float v = alpha * acc[i][j][r];
        if (negAcc) v = -v;
        outB[b * sO + row * N + col] = (bf16_t)v;
      }
}

// ---------------- fused 128x128 NT GEMM with optional K-tail and split-N epi ----
// A1: [M,K1] rows stride K1 (batch sA1); B1: [N,K1] rows stride K1 (batch sB1).
// Optional tail (A2q!=null): 64 extra K from A2 (row stride 64; A2k used for
// cols>=negSplit) x B2 [N,64] (shared). Epilogue: col<negSplit: v=alpha*acc;
// col>=negSplit: v=colVec[col-negSplit]-alpha*acc. Outputs per half (F/B ptrs).
__global__ __launch_bounds__(256) void gemm_fused_k(
    const bf16_t* __restrict__ A1, long sA1,
    const bf16_t* __restrict__ B1, long sB1,
    int N, int K1,
    const bf16_t* __restrict__ A2q, const bf16_t* __restrict__ A2k, long sA2,
    const bf16_t* __restrict__ B2,
    float alpha, int negSplit, const float* __restrict__ colVec, long sV,
    float* __restrict__ outFa, bf16_t* __restrict__ outBa, int lda, long sOa,
    float* __restrict__ outFb, bf16_t* __restrict__ outBb, int ldb, long sOb) {
  __shared__ __align__(16) bf16_t As[128 * 64];
  __shared__ __align__(16) bf16_t Bs[128 * 64];
  const int t = threadIdx.x;
  const int lane = t & 63;
  const int wave = t >> 6;
  const int wm = (wave & 1) * 64;
  const int wn = (wave >> 1) * 64;
  const long b = blockIdx.z;
  const long rowBase = (long)blockIdx.y * 128;
  const long colBase = (long)blockIdx.x * 128;
  const bf16_t* Ab = A1 + b * sA1;
  const bf16_t* Bb = B1 + b * sB1;

  floatx4 acc[4][4];
#pragma unroll
  for (int i = 0; i < 4; ++i)
#pragma unroll
    for (int j = 0; j < 4; ++j) acc[i][j] = {0.f, 0.f, 0.f, 0.f};

  const int srow = lane >> 3;            // 0..7
  const int schunk = (lane & 7) ^ srow;  // swizzled chunk fetched by this lane
  const bf16_t* aG[4];
  const bf16_t* bG[4];
  bf16_t* aL[4];
  bf16_t* bL[4];
#pragma unroll
  for (int i = 0; i < 4; ++i) {
    int r = wave * 32 + i * 8;
    aG[i] = Ab + (rowBase + r + srow) * (long)K1 + schunk * 8;
    bG[i] = Bb + (colBase + r + srow) * (long)K1 + schunk * 8;
    aL[i] = &As[r * 64];
    bL[i] = &Bs[r * 64];
  }

  const int fr = lane & 15;
  const int hi = lane >> 4;
  int aoff[4], boff[4];
#pragma unroll
  for (int i = 0; i < 4; ++i) {
    aoff[i] = (wm + i * 16 + fr) * 64 + ((hi ^ (fr & 7)) * 8);
    boff[i] = (wn + i * 16 + fr) * 64 + ((hi ^ (fr & 7)) * 8);
  }

  for (int k0 = 0; k0 < K1; k0 += 64) {
#pragma unroll
    for (int i = 0; i < 4; ++i) {
      async_copy16(aG[i] + k0, aL[i]);
      async_copy16(bG[i] + k0, bL[i]);
    }
    __syncthreads();
#pragma unroll
    for (int ks = 0; ks < 64; ks += 32) {
      bf16x8 af[4], bf[4];
#pragma unroll
      for (int i = 0; i < 4; ++i) af[i] = *(const bf16x8*)&As[aoff[i] ^ ks];
#pragma unroll
      for (int i = 0; i < 4; ++i) bf[i] = *(const bf16x8*)&Bs[boff[i] ^ ks];
#pragma unroll
      for (int i = 0; i < 4; ++i)
#pragma unroll
        for (int j = 0; j < 4; ++j)
          acc[i][j] =
              __builtin_amdgcn_mfma_f32_16x16x32_bf16(af[i], bf[j], acc[i][j], 0, 0, 0);
    }
    __syncthreads();
  }

  // ---- optional 64-wide K tail (SV-rank term) ----
  if (A2q) {
    const bf16_t* A2 = (colBase >= negSplit) ? A2k : A2q;
    const bf16_t* A2b = A2 + b * sA2;
#pragma unroll
    for (int i = 0; i < 4; ++i) {
      int r = wave * 32 + i * 8;
      async_copy16(A2b + (rowBase + r + srow) * 64 + schunk * 8, aL[i]);
      async_copy16(B2 + (colBase + r + srow) * 64 + schunk * 8, bL[i]);
    }
    __syncthreads();
#pragma unroll
    for (int ks = 0; ks < 64; ks += 32) {
      bf16x8 af[4], bf[4];
#pragma unroll
      for (int i = 0; i < 4; ++i) af[i] = *(const bf16x8*)&As[aoff[i] ^ ks];
#pragma unroll
      for (int i = 0; i < 4; ++i) bf[i] = *(const bf16x8*)&Bs[boff[i] ^ ks];
#pragma unroll
      for (int i = 0; i < 4; ++i)
#pragma unroll
        for (int j = 0; j < 4; ++j)
          acc[i][j] =
              __builtin_amdgcn_mfma_f32_16x16x32_bf16(af[i], bf[j], acc[i][j], 0, 0, 0);
    }
    __syncthreads();
  }

  // ---- epilogue ----
  const int cr = lane & 15;
  const int rq = hi * 4;
  const bool neg = (colBase >= negSplit);
  const float* cv = colVec ? (colVec + b * sV + (neg ? colBase - negSplit : colBase))
                           : nullptr;
  float* oF = neg ? outFb : outFa;
  bf16_t* oB = neg ? outBb : outBa;
  const int ld = neg ? ldb : lda;
  const long sO = neg ? sOb : sOa;
  const long cb0 = neg ? (long)(colBase - negSplit) : colBase;
#pragma unroll
  for (int i = 0; i < 4; ++i)
#pragma unroll
    for (int j = 0; j < 4; ++j)
#pragma unroll
      for (int r = 0; r < 4; ++r) {
        long row = rowBase + wm + i * 16 + rq + r;
        int c = wn + j * 16 + cr;
        float v = alpha * acc[i][j][r];
        if (neg) v = cv[c] - v;
        long o = b * sO + row * (long)ld + cb0 + c;
        if (oF) oF[o] = v;
        if (oB) oB[o] = (bf16_t)v;
      }
}

extern "C" void kernel_launch(void* const* d_in, const int* in_sizes, int n_in,
                              void* d_out, int out_size, void* d_ws, size_t ws_size,
                              hipStream_t stream) {
  const float* Q = (const float*)d_in[0];
  const float* Kin = (const float*)d_in[1];
  const float* V = (const float*)d_in[2];
  const float* W_Q = (const float*)d_in[3];
  const float* W_K = (const float*)d_in[4];
  const float* W_v = (const float*)d_in[5];
  const float* W_vq = (const float*)d_in[6];
  const float* W_vk = (const float*)d_in[7];

  float* Qout = (float*)d_out;              // [4,2048,1024]
  float* Kout = Qout + (long)B_ * S_ * E_;  // [4,2048,1024]
  float* Fout = Kout + (long)B_ * S_ * E_;  // [4,2048,2048] (logits -> f in place)

  char* w = (char*)d_ws;
  auto alloc = [&](size_t bytes) {
    char* p = w;
    w += (bytes + 255) & ~(size_t)255;
    return p;
  };
  const long BSE = (long)B_ * S_ * E_;
  bf16_t* WQKt = (bf16_t*)alloc((size_t)2 * 2 * E_ * E_);   // [WQt | WKt], each [E,E]
  bf16_t* WVt = (bf16_t*)alloc((size_t)2 * E_ * E_);        // [E,E]
  bf16_t* Wv2T = (bf16_t*)alloc((size_t)2 * 2 * E_ * SVP_); // [2E,64]: Wvq^T ; Wvk^T
  bf16_t* QtKt = (bf16_t*)alloc((size_t)2 * 2 * BSE);       // tanh(Q);tanh(K) [16384,E]
  bf16_t* Vt = (bf16_t*)alloc((size_t)2 * B_ * SVP_ * E_);  // [256,E]
  bf16_t* qkb = (bf16_t*)alloc((size_t)2 * 2 * BSE);        // q ; k   [16384,E]
  bf16_t* vb = (bf16_t*)alloc((size_t)2 * B_ * SVP_ * E_);  // v [256,E]
  bf16_t* qkT = (bf16_t*)alloc((size_t)2 * (long)B_ * 2 * E_ * S_);  // [b][2E][S]
  bf16_t* fb = (bf16_t*)alloc((size_t)2 * (long)B_ * S_ * S_);       // f bf16
  bf16_t* vqkf = (bf16_t*)alloc((size_t)2 * (long)B_ * 2 * S_ * SVP_); // [b][2S][64]
  bf16_t* q2k2 = (bf16_t*)alloc((size_t)2 * (long)B_ * S_ * 2 * E_);   // [b][S][2E]
  bf16_t* q2k2T = (bf16_t*)alloc((size_t)2 * (long)B_ * 2 * E_ * S_);  // [b][2E][S]
  float* part = (float*)alloc((size_t)4 * B_ * 8 * E_);
  float* ck = (float*)alloc((size_t)4 * B_ * E_);
  float* ck2 = (float*)alloc((size_t)4 * B_ * E_);

  bf16_t* qb = qkb;
  bf16_t* kb = qkb + BSE;

  dim3 blk256(256);
  dim3 blk32x8(32, 8);

  // ---- weight prep ----
  transp_cast_k<<<dim3(32, 32), blk32x8, 0, stream>>>(W_Q, WQKt, E_, E_, E_);
  transp_cast_k<<<dim3(32, 32), blk32x8, 0, stream>>>(W_K, WQKt + (long)E_ * E_, E_, E_, E_);
  transp_cast_k<<<dim3(32, 32), blk32x8, 0, stream>>>(W_v, WVt, E_, E_, E_);
  transp_cast_k<<<dim3(32, 2), blk32x8, 0, stream>>>(W_vq, Wv2T, SV_, E_, SVP_);
  transp_cast_k<<<dim3(32, 2), blk32x8, 0, stream>>>(W_vk, Wv2T + (long)E_ * SVP_, SV_, E_, SVP_);

  // ---- tanh + cast inputs ----
  tanh2_k<<<dim3((unsigned)(2 * BSE / 1024)), blk256, 0, stream>>>(Q, Kin, QtKt);
  tanh_vpad_k<<<dim3(B_ * SVP_ * E_ / 256), blk256, 0, stream>>>(V, Vt);

  // ---- Q,K projections fused via batch z (b=0: Qt@WQt, b=1: Kt@WKt) ----
  gemm_fused_k<<<dim3(E_ / 128, B_ * S_ / 128, 2), blk256, 0, stream>>>(
      QtKt, BSE, WQKt, (long)E_ * E_, E_, E_,
      nullptr, nullptr, 0, nullptr, 1.f, E_, nullptr, 0,
      nullptr, qkb, E_, BSE, nullptr, nullptr, 0, 0);
  // ---- V projection ----
  gemm_fused_k<<<dim3(E_ / 128, B_ * SVP_ / 128, 1), blk256, 0, stream>>>(
      Vt, 0, WVt, 0, E_, E_,
      nullptr, nullptr, 0, nullptr, 1.f, E_, nullptr, 0,
      nullptr, vb, E_, 0, nullptr, nullptr, 0, 0);

  // ---- qkT = [q^T ; k^T] per batch [2E,S] ----
  transp_bf16_k<<<dim3(E_ / 32, S_ / 32, B_), blk32x8, 0, stream>>>(
      qb, E_, (long)S_ * E_, qkT, S_, (long)2 * E_ * S_);
  transp_bf16_k<<<dim3(E_ / 32, S_ / 32, B_), blk32x8, 0, stream>>>(
      kb, E_, (long)S_ * E_, qkT + (long)E_ * S_, S_, (long)2 * E_ * S_);

  // ---- logits = q k^T / 32 -> Fout; softmax in place + fb ----
  gemm_fused_k<<<dim3(S_ / 128, S_ / 128, B_), blk256, 0, stream>>>(
      qb, (long)S_ * E_, kb, (long)S_ * E_, S_, E_,
      nullptr, nullptr, 0, nullptr, 1.f / 32.f, S_, nullptr, 0,
      Fout, nullptr, S_, (long)S_ * S_, nullptr, nullptr, 0, 0);
  softmax_row_k<<<dim3(S_, B_), blk256, 0, stream>>>(Fout, fb);

  // ---- colsum(k) ----
  colsum_part_k<<<dim3(E_ / 256, 8, B_), blk256, 0, stream>>>(kb, E_, (long)S_ * E_, part);
  colsum_fin_k<<<dim3(E_ / 256, B_), blk256, 0, stream>>>(part, ck);

  // ---- vq = q v^T/32 ; vkNeg = -k v^T/32 -> vqkf [b][2S][64] ----
  gemm_nt_k<<<dim3(1, S_ / 64, B_), blk256, 0, stream>>>(
      qb, vb, SVP_, E_, (long)S_ * E_, (long)SVP_ * E_, (long)2 * S_ * SVP_,
      1.f / 32.f, 0, vqkf);
  gemm_nt_k<<<dim3(1, S_ / 64, B_), blk256, 0, stream>>>(
      kb, vb, SVP_, E_, (long)S_ * E_, (long)SVP_ * E_, (long)2 * S_ * SVP_,
      1.f / 32.f, 1, vqkf + (long)S_ * SVP_);

  // ---- q2|k2 = [f@q + vq@Wvq | ck - (f@k - vk@Wvk)]  (one dispatch) ----
  gemm_fused_k<<<dim3(2 * E_ / 128, S_ / 128, B_), blk256, 0, stream>>>(
      fb, (long)S_ * S_, qkT, (long)2 * E_ * S_, 2 * E_, S_,
      vqkf, vqkf + (long)S_ * SVP_, (long)2 * S_ * SVP_, Wv2T,
      1.f, E_, ck, E_,
      nullptr, q2k2, 2 * E_, (long)S_ * 2 * E_,
      nullptr, q2k2 + E_, 2 * E_, (long)S_ * 2 * E_);

  // ---- q2k2T = [q2^T ; k2^T] ----
  transp_bf16_k<<<dim3(E_ / 32, S_ / 32, B_), blk32x8, 0, stream>>>(
      q2k2, 2 * E_, (long)S_ * 2 * E_, q2k2T, S_, (long)2 * E_ * S_);
  transp_bf16_k<<<dim3(E_ / 32, S_ / 32, B_), blk32x8, 0, stream>>>(
      q2k2 + E_, 2 * E_, (long)S_ * 2 * E_, q2k2T + (long)E_ * S_, S_, (long)2 * E_ * S_);

  // ---- colsum(k2) ----
  colsum_part_k<<<dim3(E_ / 256, 8, B_), blk256, 0, stream>>>(
      q2k2 + E_, 2 * E_, (long)S_ * 2 * E_, part);
  colsum_fin_k<<<dim3(E_ / 256, B_), blk256, 0, stream>>>(part, ck2);

  // ---- Q_out = f@q2 ; K_out = ck2 - f@k2  (one dispatch) ----
  gemm_fused_k<<<dim3(2 * E_ / 128, S_ / 128, B_), blk256, 0, stream>>>(
      fb, (long)S_ * S_, q2k2T, (long)2 * E_ * S_, 2 * E_, S_,
      nullptr, nullptr, 0, nullptr,
      1.f, E_, ck2, E_,
      Qout, nullptr, E_, (long)S_ * E_,
      Kout, nullptr, E_, (long)S_ * E_);
}